// Round 1
// baseline (1364.104 us; speedup 1.0000x reference)
//
#include <hip/hip_runtime.h>
#include <math.h>

#define CDIM 8192
#define DDIM 512
#define NEGF -3.0e38f
#define POSF  3.0e38f

#define BM 64
#define BN 64
#define BK 16
#define NJC 4
#define JCHUNK (CDIM / NJC) /* 2048 */

// ---- k1: reciprocal row L2 norms of gt_class_embeddings ----
// one wave per row; 2048 blocks x 256 threads
__global__ __launch_bounds__(256) void k_rnorm(const float* __restrict__ g,
                                               float* __restrict__ rn) {
    const int wave = threadIdx.x >> 6;
    const int lane = threadIdx.x & 63;
    const int row = blockIdx.x * 4 + wave;
    const float4* src = (const float4*)(g + (size_t)row * DDIM);
    const float4 a = src[lane];
    const float4 b = src[64 + lane];
    float s = a.x * a.x + a.y * a.y + a.z * a.z + a.w * a.w +
              b.x * b.x + b.y * b.y + b.z * b.z + b.w * b.w;
#pragma unroll
    for (int m = 1; m < 64; m <<= 1) s += __shfl_xor(s, m, 64);
    if (lane == 0) rn[row] = rsqrtf(s);
}

// ---- k2: fused S = G G^T tile GEMM + per-row online softmax stats ----
// grid (128, 4): blockIdx.x = 64-row block, blockIdx.y = 2048-col j-chunk.
// 256 threads as 16x16, each computing a 4x4 micro-tile of S.
// Per-row running stats (max/argmax, min/argmin, sum-exp) kept redundantly
// across the 16 tx lanes (consistent after shuffle reductions).
__global__ __launch_bounds__(256) void k_simstats(
    const float* __restrict__ g, const float* __restrict__ rn,
    float* __restrict__ pmax, float* __restrict__ pmin, float* __restrict__ pZ,
    int* __restrict__ pamax, int* __restrict__ pamin) {
    __shared__ float As[BK][BM];
    __shared__ float Bs[BK][BN];
    const int t = threadIdx.x;
    const int tx = t & 15, ty = t >> 4;
    const int i0 = blockIdx.x * BM;
    const int jbase = blockIdx.y * JCHUNK;
    const int li = t >> 2;        // tile row this thread stages (0..63)
    const int lk = (t & 3) << 2;  // float4 column offset within BK

    const float rA = rn[i0 + li];

    float m[4], mn[4], Z[4];
    int am[4], amn[4];
#pragma unroll
    for (int r = 0; r < 4; ++r) {
        m[r] = NEGF; mn[r] = POSF; Z[r] = 0.f; am[r] = 0; amn[r] = 0;
    }

    for (int jt = 0; jt < JCHUNK / BN; ++jt) {
        const int j0 = jbase + jt * BN;
        const float rB = rn[j0 + li];
        float acc[4][4];
#pragma unroll
        for (int r = 0; r < 4; ++r)
#pragma unroll
            for (int c = 0; c < 4; ++c) acc[r][c] = 0.f;

        for (int k0 = 0; k0 < DDIM; k0 += BK) {
            float4 av = *(const float4*)(g + (size_t)(i0 + li) * DDIM + k0 + lk);
            float4 bv = *(const float4*)(g + (size_t)(j0 + li) * DDIM + k0 + lk);
            av.x *= rA; av.y *= rA; av.z *= rA; av.w *= rA;
            bv.x *= rB; bv.y *= rB; bv.z *= rB; bv.w *= rB;
            __syncthreads();  // guard previous iteration's LDS reads
            As[lk + 0][li] = av.x; As[lk + 1][li] = av.y;
            As[lk + 2][li] = av.z; As[lk + 3][li] = av.w;
            Bs[lk + 0][li] = bv.x; Bs[lk + 1][li] = bv.y;
            Bs[lk + 2][li] = bv.z; Bs[lk + 3][li] = bv.w;
            __syncthreads();
#pragma unroll
            for (int kk = 0; kk < BK; ++kk) {
                const float4 a4 = *(const float4*)&As[kk][ty << 2];
                const float4 b4 = *(const float4*)&Bs[kk][tx << 2];
                const float ar[4] = {a4.x, a4.y, a4.z, a4.w};
                const float br[4] = {b4.x, b4.y, b4.z, b4.w};
#pragma unroll
                for (int r = 0; r < 4; ++r)
#pragma unroll
                    for (int c = 0; c < 4; ++c)
                        acc[r][c] = fmaf(ar[r], br[c], acc[r][c]);
            }
        }

        // ---- online stats update over this 64x64 S tile ----
#pragma unroll
        for (int r = 0; r < 4; ++r) {
            const int gi = i0 + (ty << 2) + r;
            const int gj0 = j0 + (tx << 2);
            float vmax = NEGF; int imax = gj0;
            float vmin = POSF; int imin = gj0;
#pragma unroll
            for (int q = 0; q < 4; ++q) {
                const int gj = gj0 + q;
                const bool diag = (gj == gi);
                const float v = acc[r][q];
                const float vM = diag ? NEGF : v;
                const float vm = diag ? POSF : v;
                if (vM > vmax) { vmax = vM; imax = gj; }
                if (vm < vmin) { vmin = vm; imin = gj; }
            }
            // reduce across the 16 tx lanes (xor masks stay inside the wave)
#pragma unroll
            for (int msk = 1; msk < 16; msk <<= 1) {
                const float v2 = __shfl_xor(vmax, msk, 64);
                const int i2 = __shfl_xor(imax, msk, 64);
                if (v2 > vmax || (v2 == vmax && i2 < imax)) { vmax = v2; imax = i2; }
                const float v3 = __shfl_xor(vmin, msk, 64);
                const int i3 = __shfl_xor(imin, msk, 64);
                if (v3 < vmin || (v3 == vmin && i3 < imin)) { vmin = v3; imin = i3; }
            }
            const float nm = fmaxf(m[r], vmax);
            float se = 0.f;
#pragma unroll
            for (int q = 0; q < 4; ++q) {
                const int gj = gj0 + q;
                const float v = (gj == gi) ? NEGF : acc[r][q];
                se += __expf(v - nm);  // diag: exp(-huge) underflows to 0
            }
#pragma unroll
            for (int msk = 1; msk < 16; msk <<= 1) se += __shfl_xor(se, msk, 64);
            Z[r] = Z[r] * __expf(m[r] - nm) + se;
            if (vmax > m[r]) am[r] = imax;  // strict > keeps earliest index
            m[r] = nm;
            if (vmin < mn[r]) { mn[r] = vmin; amn[r] = imin; }
        }
    }

    if (tx == 0) {
#pragma unroll
        for (int r = 0; r < 4; ++r) {
            const int gi = i0 + (ty << 2) + r;
            const int o = blockIdx.y * CDIM + gi;
            pmax[o] = m[r]; pmin[o] = mn[r]; pZ[o] = Z[r];
            pamax[o] = am[r]; pamin[o] = amn[r];
        }
    }
}

// ---- k3: merge the NJC per-row partials -> margin, ms, ls ----
__global__ __launch_bounds__(256) void k_combine(
    const float* __restrict__ pmax, const float* __restrict__ pmin,
    const float* __restrict__ pZ, const int* __restrict__ pamax,
    const int* __restrict__ pamin, float* __restrict__ margin,
    int* __restrict__ ms, int* __restrict__ ls) {
    const int row = blockIdx.x * blockDim.x + threadIdx.x;
    float M = NEGF; int aM = 0;
    float mnv = POSF; int amn = 0;
#pragma unroll
    for (int p = 0; p < NJC; ++p) {
        const int o = p * CDIM + row;
        const float v = pmax[o];
        if (v > M) { M = v; aM = pamax[o]; }  // ascending p keeps earliest j on ties
        const float u = pmin[o];
        if (u < mnv) { mnv = u; amn = pamin[o]; }
    }
    float Zt = 0.f;
#pragma unroll
    for (int p = 0; p < NJC; ++p) {
        const int o = p * CDIM + row;
        Zt += pZ[o] * __expf(pmax[o] - M);
    }
    margin[row] = (1.f - __expf(mnv - M)) / Zt;  // P[ms]-P[ls]
    ms[row] = aM;
    ls[row] = amn;
}

// ---- k4: triplet distances + mean(relu(...)) ----
// one wave per row
__global__ __launch_bounds__(256) void k_loss(
    const float* __restrict__ w, const float* __restrict__ margin,
    const int* __restrict__ ms, const int* __restrict__ ls,
    float* __restrict__ out) {
    const int wave = threadIdx.x >> 6;
    const int lane = threadIdx.x & 63;
    const int row = blockIdx.x * 4 + wave;
    const int jm = ms[row], jl = ls[row];
    const float4* wi = (const float4*)(w + (size_t)row * DDIM);
    const float4* wm = (const float4*)(w + (size_t)jm * DDIM);
    const float4* wl = (const float4*)(w + (size_t)jl * DDIM);
    float sm = 0.f, sl = 0.f;
#pragma unroll
    for (int h = 0; h < 2; ++h) {
        const int idx = h * 64 + lane;
        const float4 a = wi[idx];
        const float4 b = wm[idx];
        const float4 c = wl[idx];
        float d;
        d = a.x - b.x; sm = fmaf(d, d, sm);
        d = a.y - b.y; sm = fmaf(d, d, sm);
        d = a.z - b.z; sm = fmaf(d, d, sm);
        d = a.w - b.w; sm = fmaf(d, d, sm);
        d = a.x - c.x; sl = fmaf(d, d, sl);
        d = a.y - c.y; sl = fmaf(d, d, sl);
        d = a.z - c.z; sl = fmaf(d, d, sl);
        d = a.w - c.w; sl = fmaf(d, d, sl);
    }
#pragma unroll
    for (int msk = 1; msk < 64; msk <<= 1) {
        sm += __shfl_xor(sm, msk, 64);
        sl += __shfl_xor(sl, msk, 64);
    }
    if (lane == 0) {
        const float v = sqrtf(sm) - sqrtf(sl) + margin[row];
        if (v > 0.f) atomicAdd(out, v * (1.0f / CDIM));
    }
}

extern "C" void kernel_launch(void* const* d_in, const int* in_sizes, int n_in,
                              void* d_out, int out_size, void* d_ws, size_t ws_size,
                              hipStream_t stream) {
    const float* g = (const float*)d_in[0];  // gt_class_embeddings [8192,512]
    const float* w = (const float*)d_in[1];  // w [8192,512]
    float* out = (float*)d_out;

    // workspace layout (~0.75 MB total)
    float* p = (float*)d_ws;
    float* rn = p;        p += CDIM;
    float* pmax = p;      p += NJC * CDIM;
    float* pmin = p;      p += NJC * CDIM;
    float* pZ = p;        p += NJC * CDIM;
    int* pamax = (int*)p; p += NJC * CDIM;
    int* pamin = (int*)p; p += NJC * CDIM;
    float* margin = p;    p += CDIM;
    int* ms = (int*)p;    p += CDIM;
    int* ls = (int*)p;    p += CDIM;

    hipMemsetAsync(out, 0, sizeof(float), stream);
    k_rnorm<<<CDIM / 4, 256, 0, stream>>>(g, rn);
    dim3 g2(CDIM / BM, NJC);
    k_simstats<<<g2, 256, 0, stream>>>(g, rn, pmax, pmin, pZ, pamax, pamin);
    k_combine<<<CDIM / 256, 256, 0, stream>>>(pmax, pmin, pZ, pamax, pamin,
                                              margin, ms, ls);
    k_loss<<<CDIM / 4, 256, 0, stream>>>(w, margin, ms, ls, out);
}

// Round 2
// 464.573 us; speedup vs baseline: 2.9363x; 2.9363x over previous
//
#include <hip/hip_runtime.h>
#include <math.h>

#define CDIM 8192
#define DDIM 512
#define NEGF -3.0e38f
#define POSF  3.0e38f

#define BM 128
#define BN 128
#define BK 32
#define NJC 8
#define JCHUNK (CDIM / NJC) /* 1024 */

typedef __attribute__((ext_vector_type(8))) short bf16x8;
typedef __attribute__((ext_vector_type(4))) float f32x4;

__device__ __forceinline__ unsigned short f2bf(float x) {
    unsigned int u = __float_as_uint(x);
    u += 0x7fffu + ((u >> 16) & 1u);
    return (unsigned short)(u >> 16);
}
__device__ __forceinline__ float bf2f(unsigned short h) {
    return __uint_as_float(((unsigned int)h) << 16);
}
// async global->LDS, 16B per lane. LDS dest must be wave-uniform base + lane*16.
__device__ __forceinline__ void gld16(const void* g, void* l) {
    __builtin_amdgcn_global_load_lds(
        (__attribute__((address_space(1))) void*)(void*)g,
        (__attribute__((address_space(3))) void*)l, 16, 0, 0);
}

// ---- k_prep: normalize rows of G, split into bf16 hi/lo ----
// one wave per row
__global__ __launch_bounds__(256) void k_prep(const float* __restrict__ g,
                                              unsigned short* __restrict__ hi,
                                              unsigned short* __restrict__ lo) {
    const int wave = threadIdx.x >> 6;
    const int lane = threadIdx.x & 63;
    const int row = blockIdx.x * 4 + wave;
    const float4* src = (const float4*)(g + (size_t)row * DDIM);
    const float4 a = src[lane * 2];
    const float4 b = src[lane * 2 + 1];
    float s = a.x * a.x + a.y * a.y + a.z * a.z + a.w * a.w +
              b.x * b.x + b.y * b.y + b.z * b.z + b.w * b.w;
#pragma unroll
    for (int m = 1; m < 64; m <<= 1) s += __shfl_xor(s, m, 64);
    const float rn = rsqrtf(s);
    const float y[8] = {a.x * rn, a.y * rn, a.z * rn, a.w * rn,
                        b.x * rn, b.y * rn, b.z * rn, b.w * rn};
    unsigned int hv[4], lv[4];
#pragma unroll
    for (int i = 0; i < 4; ++i) {
        const unsigned short h0 = f2bf(y[2 * i]);
        const unsigned short h1 = f2bf(y[2 * i + 1]);
        const unsigned short l0 = f2bf(y[2 * i] - bf2f(h0));
        const unsigned short l1 = f2bf(y[2 * i + 1] - bf2f(h1));
        hv[i] = (unsigned int)h0 | ((unsigned int)h1 << 16);
        lv[i] = (unsigned int)l0 | ((unsigned int)l1 << 16);
    }
    uint4* dh = (uint4*)(hi + (size_t)row * DDIM + lane * 8);
    uint4* dl = (uint4*)(lo + (size_t)row * DDIM + lane * 8);
    *dh = make_uint4(hv[0], hv[1], hv[2], hv[3]);
    *dl = make_uint4(lv[0], lv[1], lv[2], lv[3]);
}

// ---- k_simstats: MFMA S-tiles + fused online softmax stats ----
// grid (64, NJC). 128x128 tile per block; 4 waves, wave w owns rows w*32..+32
// x all 128 cols, as 2x8 16x16 MFMA frags. 3 passes: hi*hi + hi*lo + lo*hi.
__global__ __launch_bounds__(256, 2) void k_simstats(
    const unsigned short* __restrict__ ghi, const unsigned short* __restrict__ glo,
    float* __restrict__ pmax, float* __restrict__ pmin, float* __restrict__ pZ,
    int* __restrict__ pamax, int* __restrict__ pamin) {
    __shared__ unsigned short As[BM * BK];  // 128x32 bf16, row-major, 8 KB
    __shared__ unsigned short Bs[BN * BK];
    const int t = threadIdx.x;
    const int wave = t >> 6;
    const int lane = t & 63;
    const int lanelo = lane & 15;
    const int quad = lane >> 4;
    const int i0 = blockIdx.x * BM;
    const int jbase = blockIdx.y * JCHUNK;

    // staging geometry: thread t stages bytes [t*16, t*16+16) of each 4KB half
    const int srow = t >> 2;            // tile row (0..63) for round 0
    const int scolb = (t & 3) * 16;     // byte offset within the 64B row
    char* lA0 = (char*)As + t * 16;
    char* lA1 = lA0 + 4096;
    char* lB0 = (char*)Bs + t * 16;
    char* lB1 = lB0 + 4096;

    const unsigned short* pa_tab[3] = {ghi, ghi, glo};
    const unsigned short* pb_tab[3] = {ghi, glo, ghi};

    // ds_read offsets (ushort elements) for A fragments
    const int aoff0 = (wave * 32 + lanelo) * BK + quad * 8;
    const int aoff1 = aoff0 + 16 * BK;

    // per-lane online stats for rows (rt, reg), redundant across the 16
    // lanes of each quad
    float m[2][4], mn[2][4], Z[2][4];
    int am[2][4], amn[2][4];
#pragma unroll
    for (int rt = 0; rt < 2; ++rt)
#pragma unroll
        for (int r = 0; r < 4; ++r) {
            m[rt][r] = NEGF; mn[rt][r] = POSF; Z[rt][r] = 0.f;
            am[rt][r] = 0x7fffffff; amn[rt][r] = 0x7fffffff;
        }

    for (int jt = 0; jt < JCHUNK / BN; ++jt) {
        const int j0 = jbase + jt * BN;
        f32x4 acc[2][8];
#pragma unroll
        for (int rt = 0; rt < 2; ++rt)
#pragma unroll
            for (int ct = 0; ct < 8; ++ct)
                acc[rt][ct] = (f32x4){0.f, 0.f, 0.f, 0.f};

        for (int p = 0; p < 3; ++p) {
            const char* pa0 = (const char*)pa_tab[p] +
                              (size_t)(i0 + srow) * (DDIM * 2) + scolb;
            const char* pa1 = pa0 + (size_t)64 * (DDIM * 2);
            const char* pb0 = (const char*)pb_tab[p] +
                              (size_t)(j0 + srow) * (DDIM * 2) + scolb;
            const char* pb1 = pb0 + (size_t)64 * (DDIM * 2);

            for (int k0 = 0; k0 < DDIM; k0 += BK) {
                __syncthreads();  // previous iter's frag reads done
                gld16(pa0 + k0 * 2, lA0);
                gld16(pa1 + k0 * 2, lA1);
                gld16(pb0 + k0 * 2, lB0);
                gld16(pb1 + k0 * 2, lB1);
                __syncthreads();  // drains vmcnt: staged data visible
                const bf16x8 af0 = *(const bf16x8*)&As[aoff0];
                const bf16x8 af1 = *(const bf16x8*)&As[aoff1];
#pragma unroll
                for (int ct = 0; ct < 8; ++ct) {
                    const bf16x8 bfr =
                        *(const bf16x8*)&Bs[(ct * 16 + lanelo) * BK + quad * 8];
                    acc[0][ct] = __builtin_amdgcn_mfma_f32_16x16x32_bf16(
                        af0, bfr, acc[0][ct], 0, 0, 0);
                    acc[1][ct] = __builtin_amdgcn_mfma_f32_16x16x32_bf16(
                        af1, bfr, acc[1][ct], 0, 0, 0);
                }
            }
        }

        // ---- online stats over this 128x128 S tile ----
        // C/D layout: col = lanelo, row = quad*4 + reg  [m89]
#pragma unroll
        for (int rt = 0; rt < 2; ++rt) {
#pragma unroll
            for (int r = 0; r < 4; ++r) {
                const int gi = i0 + wave * 32 + rt * 16 + quad * 4 + r;
                float vmax = NEGF; int imax = 0x7fffffff;
                float vmin = POSF; int imin = 0x7fffffff;
#pragma unroll
                for (int ct = 0; ct < 8; ++ct) {
                    const int gj = j0 + ct * 16 + lanelo;
                    const float v = acc[rt][ct][r];
                    const bool diag = (gj == gi);
                    const float vM = diag ? NEGF : v;
                    const float vm = diag ? POSF : v;
                    if (vM > vmax) { vmax = vM; imax = gj; }
                    if (vm < vmin) { vmin = vm; imin = gj; }
                }
#pragma unroll
                for (int msk = 1; msk < 16; msk <<= 1) {
                    const float v2 = __shfl_xor(vmax, msk, 64);
                    const int i2 = __shfl_xor(imax, msk, 64);
                    if (v2 > vmax || (v2 == vmax && i2 < imax)) { vmax = v2; imax = i2; }
                    const float v3 = __shfl_xor(vmin, msk, 64);
                    const int i3 = __shfl_xor(imin, msk, 64);
                    if (v3 < vmin || (v3 == vmin && i3 < imin)) { vmin = v3; imin = i3; }
                }
                const float nm = fmaxf(m[rt][r], vmax);
                float se = 0.f;
#pragma unroll
                for (int ct = 0; ct < 8; ++ct) {
                    const int gj = j0 + ct * 16 + lanelo;
                    const float v = (gj == gi) ? NEGF : acc[rt][ct][r];
                    se += __expf(v - nm);  // diag underflows to 0
                }
#pragma unroll
                for (int msk = 1; msk < 16; msk <<= 1) se += __shfl_xor(se, msk, 64);
                Z[rt][r] = Z[rt][r] * __expf(m[rt][r] - nm) + se;
                if (vmax > m[rt][r]) am[rt][r] = imax;  // strict >: earliest jt wins ties
                m[rt][r] = nm;
                if (vmin < mn[rt][r]) { mn[rt][r] = vmin; amn[rt][r] = imin; }
            }
        }
    }

    if (lanelo == 0) {
#pragma unroll
        for (int rt = 0; rt < 2; ++rt)
#pragma unroll
            for (int r = 0; r < 4; ++r) {
                const int gi = i0 + wave * 32 + rt * 16 + quad * 4 + r;
                const int o = blockIdx.y * CDIM + gi;
                pmax[o] = m[rt][r]; pmin[o] = mn[rt][r]; pZ[o] = Z[rt][r];
                pamax[o] = am[rt][r]; pamin[o] = amn[rt][r];
            }
    }
}

// ---- k_combine: merge NJC per-row partials -> margin, ms, ls ----
__global__ __launch_bounds__(256) void k_combine(
    const float* __restrict__ pmax, const float* __restrict__ pmin,
    const float* __restrict__ pZ, const int* __restrict__ pamax,
    const int* __restrict__ pamin, float* __restrict__ margin,
    int* __restrict__ ms, int* __restrict__ ls) {
    const int row = blockIdx.x * blockDim.x + threadIdx.x;
    float M = NEGF; int aM = 0;
    float mnv = POSF; int amn = 0;
#pragma unroll
    for (int p = 0; p < NJC; ++p) {
        const int o = p * CDIM + row;
        const float v = pmax[o];
        if (v > M) { M = v; aM = pamax[o]; }  // ascending p: earliest j on ties
        const float u = pmin[o];
        if (u < mnv) { mnv = u; amn = pamin[o]; }
    }
    float Zt = 0.f;
#pragma unroll
    for (int p = 0; p < NJC; ++p) {
        const int o = p * CDIM + row;
        Zt += pZ[o] * __expf(pmax[o] - M);
    }
    margin[row] = (1.f - __expf(mnv - M)) / Zt;  // P[ms] - P[ls]
    ms[row] = aM;
    ls[row] = amn;
}

// ---- k_loss: triplet distances + mean(relu(...)) ----
__global__ __launch_bounds__(256) void k_loss(
    const float* __restrict__ w, const float* __restrict__ margin,
    const int* __restrict__ ms, const int* __restrict__ ls,
    float* __restrict__ out) {
    const int wave = threadIdx.x >> 6;
    const int lane = threadIdx.x & 63;
    const int row = blockIdx.x * 4 + wave;
    const int jm = ms[row], jl = ls[row];
    const float4* wi = (const float4*)(w + (size_t)row * DDIM);
    const float4* wm = (const float4*)(w + (size_t)jm * DDIM);
    const float4* wl = (const float4*)(w + (size_t)jl * DDIM);
    float sm = 0.f, sl = 0.f;
#pragma unroll
    for (int h = 0; h < 2; ++h) {
        const int idx = h * 64 + lane;
        const float4 a = wi[idx];
        const float4 b = wm[idx];
        const float4 c = wl[idx];
        float d;
        d = a.x - b.x; sm = fmaf(d, d, sm);
        d = a.y - b.y; sm = fmaf(d, d, sm);
        d = a.z - b.z; sm = fmaf(d, d, sm);
        d = a.w - b.w; sm = fmaf(d, d, sm);
        d = a.x - c.x; sl = fmaf(d, d, sl);
        d = a.y - c.y; sl = fmaf(d, d, sl);
        d = a.z - c.z; sl = fmaf(d, d, sl);
        d = a.w - c.w; sl = fmaf(d, d, sl);
    }
#pragma unroll
    for (int msk = 1; msk < 64; msk <<= 1) {
        sm += __shfl_xor(sm, msk, 64);
        sl += __shfl_xor(sl, msk, 64);
    }
    if (lane == 0) {
        const float v = sqrtf(sm) - sqrtf(sl) + margin[row];
        if (v > 0.f) atomicAdd(out, v * (1.0f / CDIM));
    }
}

extern "C" void kernel_launch(void* const* d_in, const int* in_sizes, int n_in,
                              void* d_out, int out_size, void* d_ws, size_t ws_size,
                              hipStream_t stream) {
    const float* g = (const float*)d_in[0];  // gt_class_embeddings [8192,512]
    const float* w = (const float*)d_in[1];  // w [8192,512]
    float* out = (float*)d_out;

    // workspace layout (~18 MB)
    unsigned short* ghi = (unsigned short*)d_ws;
    unsigned short* glo = ghi + (size_t)CDIM * DDIM;
    float* p = (float*)(glo + (size_t)CDIM * DDIM);
    float* pmax = p;      p += NJC * CDIM;
    float* pmin = p;      p += NJC * CDIM;
    float* pZ = p;        p += NJC * CDIM;
    int* pamax = (int*)p; p += NJC * CDIM;
    int* pamin = (int*)p; p += NJC * CDIM;
    float* margin = p;    p += CDIM;
    int* ms = (int*)p;    p += CDIM;
    int* ls = (int*)p;    p += CDIM;

    hipMemsetAsync(out, 0, sizeof(float), stream);
    k_prep<<<CDIM / 4, 256, 0, stream>>>(g, ghi, glo);
    dim3 g2(CDIM / BM, NJC);
    k_simstats<<<g2, 256, 0, stream>>>(ghi, glo, pmax, pmin, pZ, pamax, pamin);
    k_combine<<<CDIM / 256, 256, 0, stream>>>(pmax, pmin, pZ, pamax, pamin,
                                              margin, ms, ls);
    k_loss<<<CDIM / 4, 256, 0, stream>>>(w, margin, ms, ls, out);
}

// Round 3
// 455.177 us; speedup vs baseline: 2.9969x; 1.0206x over previous
//
#include <hip/hip_runtime.h>
#include <math.h>

#define CDIM 8192
#define DDIM 512
#define NEGF -3.0e38f
#define POSF  3.0e38f

#define BM 128
#define BN 128
#define BK 32
#define NJC 16
#define JCHUNK (CDIM / NJC) /* 512 */

typedef __attribute__((ext_vector_type(8))) short bf16x8;
typedef __attribute__((ext_vector_type(4))) float f32x4;

__device__ __forceinline__ unsigned short f2bf(float x) {
    unsigned int u = __float_as_uint(x);
    u += 0x7fffu + ((u >> 16) & 1u);
    return (unsigned short)(u >> 16);
}
__device__ __forceinline__ float bf2f(unsigned short h) {
    return __uint_as_float(((unsigned int)h) << 16);
}
// async global->LDS, 16B per lane. LDS dest is wave-uniform base + lane*16.
__device__ __forceinline__ void gld16(const void* g, void* l) {
    __builtin_amdgcn_global_load_lds(
        (__attribute__((address_space(1))) void*)(void*)g,
        (__attribute__((address_space(3))) void*)l, 16, 0, 0);
}

// ---- k_prep: normalize rows of G, split into bf16 hi/lo ----
__global__ __launch_bounds__(256) void k_prep(const float* __restrict__ g,
                                              unsigned short* __restrict__ hi,
                                              unsigned short* __restrict__ lo) {
    const int wave = threadIdx.x >> 6;
    const int lane = threadIdx.x & 63;
    const int row = blockIdx.x * 4 + wave;
    const float4* src = (const float4*)(g + (size_t)row * DDIM);
    const float4 a = src[lane * 2];
    const float4 b = src[lane * 2 + 1];
    float s = a.x * a.x + a.y * a.y + a.z * a.z + a.w * a.w +
              b.x * b.x + b.y * b.y + b.z * b.z + b.w * b.w;
#pragma unroll
    for (int m = 1; m < 64; m <<= 1) s += __shfl_xor(s, m, 64);
    const float rn = rsqrtf(s);
    const float y[8] = {a.x * rn, a.y * rn, a.z * rn, a.w * rn,
                        b.x * rn, b.y * rn, b.z * rn, b.w * rn};
    unsigned int hv[4], lv[4];
#pragma unroll
    for (int i = 0; i < 4; ++i) {
        const unsigned short h0 = f2bf(y[2 * i]);
        const unsigned short h1 = f2bf(y[2 * i + 1]);
        const unsigned short l0 = f2bf(y[2 * i] - bf2f(h0));
        const unsigned short l1 = f2bf(y[2 * i + 1] - bf2f(h1));
        hv[i] = (unsigned int)h0 | ((unsigned int)h1 << 16);
        lv[i] = (unsigned int)l0 | ((unsigned int)l1 << 16);
    }
    uint4* dh = (uint4*)(hi + (size_t)row * DDIM + lane * 8);
    uint4* dl = (uint4*)(lo + (size_t)row * DDIM + lane * 8);
    *dh = make_uint4(hv[0], hv[1], hv[2], hv[3]);
    *dl = make_uint4(lv[0], lv[1], lv[2], lv[3]);
}

// ---- k_simstats: MFMA S-tiles + per-lane online softmax stats ----
// grid (64, NJC). 128x128 tile per block; wave w owns rows w*32..+32 x 128
// cols as 2x8 16x16x32 frags. 3 passes: hi*hi + hi*lo + lo*hi.
// LDS layout XOR-swizzled at the global-source side: LDS slot (row, c)
// holds global chunk c ^ ((row>>1)&3)  (16B chunks, 4 per 64B row).
__global__ __launch_bounds__(256, 3) void k_simstats(
    const unsigned short* __restrict__ ghi, const unsigned short* __restrict__ glo,
    float* __restrict__ pmax, float* __restrict__ pmin, float* __restrict__ pZ,
    int* __restrict__ pamax, int* __restrict__ pamin) {
    __shared__ unsigned short As[BM * BK];  // 8 KB
    __shared__ unsigned short Bs[BN * BK];  // 8 KB
    const int t = threadIdx.x;
    const int wave = t >> 6;
    const int lane = t & 63;
    const int lanelo = lane & 15;
    const int quad = lane >> 4;
    const int i0 = blockIdx.x * BM;
    const int jbase = blockIdx.y * JCHUNK;

    // staging: thread t fills LDS slot t*16 with global chunk swizzled
    const int srow = t >> 2;                        // tile row 0..63 (per half)
    const int scolb = ((t & 3) ^ ((t >> 3) & 3)) * 16;  // swizzled source chunk
    char* lA0 = (char*)As + t * 16;
    char* lA1 = lA0 + 4096;
    char* lB0 = (char*)Bs + t * 16;
    char* lB1 = lB0 + 4096;

    const unsigned short* pa_tab[3] = {ghi, ghi, glo};
    const unsigned short* pb_tab[3] = {ghi, glo, ghi};

    // frag-read offsets (ushort units), loop-invariant; swz kills bank conflicts
    const int swz = quad ^ ((lanelo >> 1) & 3);
    const int aoff0 = (wave * 32 + lanelo) * BK + swz * 8;
    const int aoff1 = aoff0 + 16 * BK;
    const int boff = lanelo * BK + swz * 8;  // + ct*16*BK via imm offset

    // per-lane online stats for rows (rt, r); merged across 16 lanes at end
    float m[2][4], mn[2][4], Z[2][4];
    int am[2][4], amn[2][4];
#pragma unroll
    for (int rt = 0; rt < 2; ++rt)
#pragma unroll
        for (int r = 0; r < 4; ++r) {
            m[rt][r] = NEGF; mn[rt][r] = POSF; Z[rt][r] = 0.f;
            am[rt][r] = 0x7fffffff; amn[rt][r] = 0x7fffffff;
        }

    for (int jt = 0; jt < JCHUNK / BN; ++jt) {
        const int j0 = jbase + jt * BN;
        f32x4 acc[2][8];
#pragma unroll
        for (int rt = 0; rt < 2; ++rt)
#pragma unroll
            for (int ct = 0; ct < 8; ++ct)
                acc[rt][ct] = (f32x4){0.f, 0.f, 0.f, 0.f};

        for (int p = 0; p < 3; ++p) {
            const char* pa0 = (const char*)pa_tab[p] +
                              (size_t)(i0 + srow) * (DDIM * 2) + scolb;
            const char* pa1 = pa0 + (size_t)64 * (DDIM * 2);
            const char* pb0 = (const char*)pb_tab[p] +
                              (size_t)(j0 + srow) * (DDIM * 2) + scolb;
            const char* pb1 = pb0 + (size_t)64 * (DDIM * 2);

            for (int k0 = 0; k0 < DDIM; k0 += BK) {
                __syncthreads();  // previous iter's frag reads done
                gld16(pa0 + k0 * 2, lA0);
                gld16(pa1 + k0 * 2, lA1);
                gld16(pb0 + k0 * 2, lB0);
                gld16(pb1 + k0 * 2, lB1);
                __syncthreads();  // drains vmcnt: staged data visible
                const bf16x8 af0 = *(const bf16x8*)&As[aoff0];
                const bf16x8 af1 = *(const bf16x8*)&As[aoff1];
#pragma unroll
                for (int ct = 0; ct < 8; ++ct) {
                    const bf16x8 bfr = *(const bf16x8*)&Bs[boff + ct * 16 * BK];
                    acc[0][ct] = __builtin_amdgcn_mfma_f32_16x16x32_bf16(
                        af0, bfr, acc[0][ct], 0, 0, 0);
                    acc[1][ct] = __builtin_amdgcn_mfma_f32_16x16x32_bf16(
                        af1, bfr, acc[1][ct], 0, 0, 0);
                }
            }
        }

        // ---- per-lane online stats over this 128x128 S tile ----
        // C/D layout: col = lanelo, row = quad*4 + reg  [m89]
        const bool hasdiag = (i0 < j0 + BN) && (j0 < i0 + BM);
        auto epi = [&](bool DIAG) {
#pragma unroll
            for (int rt = 0; rt < 2; ++rt) {
#pragma unroll
                for (int r = 0; r < 4; ++r) {
                    const int gi = i0 + wave * 32 + rt * 16 + quad * 4 + r;
                    float tmax = NEGF; int targ = 0x7fffffff;
                    float tmin = POSF; int targn = 0x7fffffff;
                    float vv[8];
#pragma unroll
                    for (int ct = 0; ct < 8; ++ct) {
                        const int gj = j0 + ct * 16 + lanelo;
                        const float v = acc[rt][ct][r];
                        const bool dg = DIAG && (gj == gi);
                        const float vM = dg ? NEGF : v;
                        const float vm = dg ? POSF : v;
                        vv[ct] = vM;
                        if (vM > tmax) { tmax = vM; targ = gj; }
                        if (vm < tmin) { tmin = vm; targn = gj; }
                    }
                    const float nm = fmaxf(m[rt][r], tmax);
                    float se = 0.f;
#pragma unroll
                    for (int ct = 0; ct < 8; ++ct) se += __expf(vv[ct] - nm);
                    Z[rt][r] = fmaf(Z[rt][r], __expf(m[rt][r] - nm), se);
                    if (tmax > m[rt][r]) am[rt][r] = targ;  // strict >: earliest j
                    m[rt][r] = nm;
                    if (tmin < mn[rt][r]) { mn[rt][r] = tmin; amn[rt][r] = targn; }
                }
            }
        };
        if (hasdiag) epi(true); else epi(false);
    }

    // ---- final cross-lane (16) merge + write partials ----
#pragma unroll
    for (int rt = 0; rt < 2; ++rt) {
#pragma unroll
        for (int r = 0; r < 4; ++r) {
            float vmax = m[rt][r]; int imax = am[rt][r];
            float vmin = mn[rt][r]; int imin = amn[rt][r];
#pragma unroll
            for (int msk = 1; msk < 16; msk <<= 1) {
                const float v2 = __shfl_xor(vmax, msk, 64);
                const int i2 = __shfl_xor(imax, msk, 64);
                if (v2 > vmax || (v2 == vmax && i2 < imax)) { vmax = v2; imax = i2; }
                const float v3 = __shfl_xor(vmin, msk, 64);
                const int i3 = __shfl_xor(imin, msk, 64);
                if (v3 < vmin || (v3 == vmin && i3 < imin)) { vmin = v3; imin = i3; }
            }
            // vmax is now the row's global max on all lanes; merge Z
            float zs = Z[rt][r] * __expf(m[rt][r] - vmax);
#pragma unroll
            for (int msk = 1; msk < 16; msk <<= 1) zs += __shfl_xor(zs, msk, 64);
            if (lanelo == 0) {
                const int gi = i0 + wave * 32 + rt * 16 + quad * 4 + r;
                const int o = blockIdx.y * CDIM + gi;
                pmax[o] = vmax; pmin[o] = vmin; pZ[o] = zs;
                pamax[o] = imax; pamin[o] = imin;
            }
        }
    }
}

// ---- k_combine: merge NJC per-row partials -> margin, ms, ls ----
__global__ __launch_bounds__(256) void k_combine(
    const float* __restrict__ pmax, const float* __restrict__ pmin,
    const float* __restrict__ pZ, const int* __restrict__ pamax,
    const int* __restrict__ pamin, float* __restrict__ margin,
    int* __restrict__ ms, int* __restrict__ ls) {
    const int row = blockIdx.x * blockDim.x + threadIdx.x;
    float M = NEGF; int aM = 0;
    float mnv = POSF; int amn = 0;
#pragma unroll
    for (int p = 0; p < NJC; ++p) {
        const int o = p * CDIM + row;
        const float v = pmax[o];
        if (v > M) { M = v; aM = pamax[o]; }  // ascending p: earliest j on ties
        const float u = pmin[o];
        if (u < mnv) { mnv = u; amn = pamin[o]; }
    }
    float Zt = 0.f;
#pragma unroll
    for (int p = 0; p < NJC; ++p) {
        const int o = p * CDIM + row;
        Zt += pZ[o] * __expf(pmax[o] - M);
    }
    margin[row] = (1.f - __expf(mnv - M)) / Zt;  // P[ms] - P[ls]
    ms[row] = aM;
    ls[row] = amn;
}

// ---- k_loss: triplet distances + mean(relu(...)) ----
__global__ __launch_bounds__(256) void k_loss(
    const float* __restrict__ w, const float* __restrict__ margin,
    const int* __restrict__ ms, const int* __restrict__ ls,
    float* __restrict__ out) {
    const int wave = threadIdx.x >> 6;
    const int lane = threadIdx.x & 63;
    const int row = blockIdx.x * 4 + wave;
    const int jm = ms[row], jl = ls[row];
    const float4* wi = (const float4*)(w + (size_t)row * DDIM);
    const float4* wm = (const float4*)(w + (size_t)jm * DDIM);
    const float4* wl = (const float4*)(w + (size_t)jl * DDIM);
    float sm = 0.f, sl = 0.f;
#pragma unroll
    for (int h = 0; h < 2; ++h) {
        const int idx = h * 64 + lane;
        const float4 a = wi[idx];
        const float4 b = wm[idx];
        const float4 c = wl[idx];
        float d;
        d = a.x - b.x; sm = fmaf(d, d, sm);
        d = a.y - b.y; sm = fmaf(d, d, sm);
        d = a.z - b.z; sm = fmaf(d, d, sm);
        d = a.w - b.w; sm = fmaf(d, d, sm);
        d = a.x - c.x; sl = fmaf(d, d, sl);
        d = a.y - c.y; sl = fmaf(d, d, sl);
        d = a.z - c.z; sl = fmaf(d, d, sl);
        d = a.w - c.w; sl = fmaf(d, d, sl);
    }
#pragma unroll
    for (int msk = 1; msk < 64; msk <<= 1) {
        sm += __shfl_xor(sm, msk, 64);
        sl += __shfl_xor(sl, msk, 64);
    }
    if (lane == 0) {
        const float v = sqrtf(sm) - sqrtf(sl) + margin[row];
        if (v > 0.f) atomicAdd(out, v * (1.0f / CDIM));
    }
}

extern "C" void kernel_launch(void* const* d_in, const int* in_sizes, int n_in,
                              void* d_out, int out_size, void* d_ws, size_t ws_size,
                              hipStream_t stream) {
    const float* g = (const float*)d_in[0];  // gt_class_embeddings [8192,512]
    const float* w = (const float*)d_in[1];  // w [8192,512]
    float* out = (float*)d_out;

    // workspace layout (~19 MB)
    unsigned short* ghi = (unsigned short*)d_ws;
    unsigned short* glo = ghi + (size_t)CDIM * DDIM;
    float* p = (float*)(glo + (size_t)CDIM * DDIM);
    float* pmax = p;      p += NJC * CDIM;
    float* pmin = p;      p += NJC * CDIM;
    float* pZ = p;        p += NJC * CDIM;
    int* pamax = (int*)p; p += NJC * CDIM;
    int* pamin = (int*)p; p += NJC * CDIM;
    float* margin = p;    p += CDIM;
    int* ms = (int*)p;    p += CDIM;
    int* ls = (int*)p;    p += CDIM;

    hipMemsetAsync(out, 0, sizeof(float), stream);
    k_prep<<<CDIM / 4, 256, 0, stream>>>(g, ghi, glo);
    dim3 g2(CDIM / BM, NJC);
    k_simstats<<<g2, 256, 0, stream>>>(ghi, glo, pmax, pmin, pZ, pamax, pamin);
    k_combine<<<CDIM / 256, 256, 0, stream>>>(pmax, pmin, pZ, pamax, pamin,
                                              margin, ms, ls);
    k_loss<<<CDIM / 4, 256, 0, stream>>>(w, margin, ms, ls, out);
}

// Round 5
// 326.398 us; speedup vs baseline: 4.1793x; 1.3945x over previous
//
#include <hip/hip_runtime.h>
#include <math.h>

#define CDIM 8192
#define DDIM 512
#define NEGF -3.0e38f
#define POSF  3.0e38f

#define BM 128
#define BN 256
#define BK 64
#define NP (CDIM / BN) /* 32 j-chunks, one per blockIdx.y */

typedef __attribute__((ext_vector_type(8))) short bf16x8;
typedef __attribute__((ext_vector_type(4))) float f32x4;

__device__ __forceinline__ unsigned short f2bf(float x) {
    unsigned int u = __float_as_uint(x);
    u += 0x7fffu + ((u >> 16) & 1u);
    return (unsigned short)(u >> 16);
}
__device__ __forceinline__ float bf2f(unsigned short h) {
    return __uint_as_float(((unsigned int)h) << 16);
}
// async global->LDS, 16B per lane. LDS dest is wave-uniform base + lane*16.
__device__ __forceinline__ void gld16(const void* g, void* l) {
    __builtin_amdgcn_global_load_lds(
        (__attribute__((address_space(1))) void*)(void*)g,
        (__attribute__((address_space(3))) void*)l, 16, 0, 0);
}

// ---- k_prep: normalize rows of G, split into bf16 hi/lo ----
__global__ __launch_bounds__(256) void k_prep(const float* __restrict__ g,
                                              unsigned short* __restrict__ hi,
                                              unsigned short* __restrict__ lo) {
    const int wave = threadIdx.x >> 6;
    const int lane = threadIdx.x & 63;
    const int row = blockIdx.x * 4 + wave;
    const float4* src = (const float4*)(g + (size_t)row * DDIM);
    const float4 a = src[lane * 2];
    const float4 b = src[lane * 2 + 1];
    float s = a.x * a.x + a.y * a.y + a.z * a.z + a.w * a.w +
              b.x * b.x + b.y * b.y + b.z * b.z + b.w * b.w;
#pragma unroll
    for (int m = 1; m < 64; m <<= 1) s += __shfl_xor(s, m, 64);
    const float rn = rsqrtf(s);
    const float y[8] = {a.x * rn, a.y * rn, a.z * rn, a.w * rn,
                        b.x * rn, b.y * rn, b.z * rn, b.w * rn};
    unsigned int hv[4], lv[4];
#pragma unroll
    for (int i = 0; i < 4; ++i) {
        const unsigned short h0 = f2bf(y[2 * i]);
        const unsigned short h1 = f2bf(y[2 * i + 1]);
        const unsigned short l0 = f2bf(y[2 * i] - bf2f(h0));
        const unsigned short l1 = f2bf(y[2 * i + 1] - bf2f(h1));
        hv[i] = (unsigned int)h0 | ((unsigned int)h1 << 16);
        lv[i] = (unsigned int)l0 | ((unsigned int)l1 << 16);
    }
    uint4* dh = (uint4*)(hi + (size_t)row * DDIM + lane * 8);
    uint4* dl = (uint4*)(lo + (size_t)row * DDIM + lane * 8);
    *dh = make_uint4(hv[0], hv[1], hv[2], hv[3]);
    *dl = make_uint4(lv[0], lv[1], lv[2], lv[3]);
}

// ---- k_simstats: MFMA S-tiles + per-row softmax stats ----
// grid (64, 32). Block tile 128x256 (one j-tile). 4 waves as 2x2: wave
// (wr,wc) owns rows wr*64..+64 x cols wc*128..+128 as 4x8 16x16x32 frags.
// 3 passes: hi*hi + hi*lo + lo*hi (K=512 each), BK=64 per barrier pair.
// LDS rows are 128 B (8 chunks of 16 B); slot c holds source chunk
// c ^ (row&7) so frag b128 reads spread over all 8 bank groups (2-way=free).
// RACE FIX (round 5): waves (wr,0) and (wr,1) cover the same rows with
// different column halves -> merge through LDS before the global write.
__global__ __launch_bounds__(256, 2) void k_simstats(
    const unsigned short* __restrict__ ghi, const unsigned short* __restrict__ glo,
    float* __restrict__ pmax, float* __restrict__ pmin, float* __restrict__ pZ,
    int* __restrict__ pamax, int* __restrict__ pamin) {
    __shared__ unsigned short As[BM * BK];  // 16 KB
    __shared__ unsigned short Bs[BN * BK];  // 32 KB
    const int t = threadIdx.x;
    const int wave = t >> 6;
    const int lane = t & 63;
    const int lanelo = lane & 15;
    const int quad = lane >> 4;
    const int wr = wave & 1;
    const int wc = wave >> 1;
    const int i0 = blockIdx.x * BM;
    const int j0 = blockIdx.y * BN;

    // staging: thread t covers byte t*16 + q*4096 -> row (t>>3)+q*32, slot t&7
    const int srow = t >> 3;
    const int scolb = ((t & 7) ^ ((t >> 3) & 7)) << 4;  // swizzled source chunk
    char* lA = (char*)As + t * 16;
    char* lB = (char*)Bs + t * 16;

    const unsigned short* pa_tab[3] = {ghi, ghi, glo};
    const unsigned short* pb_tab[3] = {ghi, glo, ghi};

    f32x4 acc[4][8];
#pragma unroll
    for (int rt = 0; rt < 4; ++rt)
#pragma unroll
        for (int ct = 0; ct < 8; ++ct)
            acc[rt][ct] = (f32x4){0.f, 0.f, 0.f, 0.f};

    // frag-read row offsets (ushort units); slot depends on (ks,quad,lanelo)
    const int arow0 = (wr * 64 + lanelo) * BK;        // + rt*16*BK
    const int brow0 = (wc * 128 + lanelo) * BK;       // + ct*16*BK
    const int l7 = lanelo & 7;

    for (int p = 0; p < 3; ++p) {
        const char* baseA = (const char*)pa_tab[p] +
                            (size_t)(i0 + srow) * (DDIM * 2) + scolb;
        const char* baseB = (const char*)pb_tab[p] +
                            (size_t)(j0 + srow) * (DDIM * 2) + scolb;
        for (int k0 = 0; k0 < DDIM; k0 += BK) {
            __syncthreads();  // previous iter's frag reads done
#pragma unroll
            for (int q = 0; q < 4; ++q)
                gld16(baseA + (size_t)q * 32 * (DDIM * 2) + k0 * 2, lA + q * 4096);
#pragma unroll
            for (int q = 0; q < 8; ++q)
                gld16(baseB + (size_t)q * 32 * (DDIM * 2) + k0 * 2, lB + q * 4096);
            __syncthreads();  // drains vmcnt: staged data visible
#pragma unroll
            for (int ks = 0; ks < 2; ++ks) {
                const int sl8 = ((((ks << 2) + quad) ^ l7) << 3);
                bf16x8 af[4];
#pragma unroll
                for (int rt = 0; rt < 4; ++rt)
                    af[rt] = *(const bf16x8*)&As[arow0 + rt * 16 * BK + sl8];
#pragma unroll
                for (int ct = 0; ct < 8; ++ct) {
                    const bf16x8 bfr = *(const bf16x8*)&Bs[brow0 + ct * 16 * BK + sl8];
#pragma unroll
                    for (int rt = 0; rt < 4; ++rt)
                        acc[rt][ct] = __builtin_amdgcn_mfma_f32_16x16x32_bf16(
                            af[rt], bfr, acc[rt][ct], 0, 0, 0);
                }
            }
        }
    }

    // ---- per-wave stats over its 64x128 sub-tile -> LDS merge buffers ----
    // C/D layout: col = lanelo, row = quad*4 + reg  [m89]
    float* mbuf   = (float*)As;        // [2][128]
    float* zbuf   = mbuf + 256;        // [2][128]
    float* mnbuf  = zbuf + 256;        // [2][128]
    int*   ambuf  = (int*)(mnbuf + 256);
    int*   amnbuf = ambuf + 256;       // total 5 KB, overlays As

    __syncthreads();  // all waves' last-iter LDS reads done before reuse

    const bool hasdiag = (i0 < j0 + BN) && (j0 < i0 + BM);
#pragma unroll
    for (int rt = 0; rt < 4; ++rt) {
#pragma unroll
        for (int r = 0; r < 4; ++r) {
            const int lrow = wr * 64 + rt * 16 + quad * 4 + r;  // block row
            const int gi = i0 + lrow;
            float tmax = NEGF; int targ = 0x7fffffff;
            float tmin = POSF; int targn = 0x7fffffff;
            float vv[8];
#pragma unroll
            for (int ct = 0; ct < 8; ++ct) {
                const int gj = j0 + wc * 128 + ct * 16 + lanelo;
                const float v = acc[rt][ct][r];
                const bool dg = hasdiag && (gj == gi);
                const float vM = dg ? NEGF : v;
                const float vm = dg ? POSF : v;
                vv[ct] = vM;
                if (vM > tmax) { tmax = vM; targ = gj; }   // ct asc = j asc
                if (vm < tmin) { tmin = vm; targn = gj; }
            }
            float se = 0.f;
#pragma unroll
            for (int ct = 0; ct < 8; ++ct) se += __expf(vv[ct] - tmax);
            // cross-lane (16) merge within the wave
            float vmax = tmax; int imax = targ;
            float vmin = tmin; int imin = targn;
#pragma unroll
            for (int msk = 1; msk < 16; msk <<= 1) {
                const float v2 = __shfl_xor(vmax, msk, 64);
                const int i2 = __shfl_xor(imax, msk, 64);
                if (v2 > vmax || (v2 == vmax && i2 < imax)) { vmax = v2; imax = i2; }
                const float v3 = __shfl_xor(vmin, msk, 64);
                const int i3 = __shfl_xor(imin, msk, 64);
                if (v3 < vmin || (v3 == vmin && i3 < imin)) { vmin = v3; imin = i3; }
            }
            float zs = se * __expf(tmax - vmax);
#pragma unroll
            for (int msk = 1; msk < 16; msk <<= 1) zs += __shfl_xor(zs, msk, 64);
            if (lanelo == 0) {
                const int o = wc * 128 + lrow;
                mbuf[o] = vmax; zbuf[o] = zs; mnbuf[o] = vmin;
                ambuf[o] = imax; amnbuf[o] = imin;
            }
        }
    }

    __syncthreads();

    // ---- merge the two column-halves; threads 0..127 own one row each ----
    if (t < BM) {
        const float m0 = mbuf[t], m1 = mbuf[128 + t];
        // wc=0 columns are all < wc=1 columns: strict compares keep the
        // smallest index on value ties (numpy first-occurrence semantics)
        float vmax = m0; int imax = ambuf[t];
        if (m1 > vmax) { vmax = m1; imax = ambuf[128 + t]; }
        float vmin = mnbuf[t]; int imin = amnbuf[t];
        if (mnbuf[128 + t] < vmin) { vmin = mnbuf[128 + t]; imin = amnbuf[128 + t]; }
        const float zs = zbuf[t] * __expf(m0 - vmax) +
                         zbuf[128 + t] * __expf(m1 - vmax);
        const int o = blockIdx.y * CDIM + i0 + t;
        pmax[o] = vmax; pmin[o] = vmin; pZ[o] = zs;
        pamax[o] = imax; pamin[o] = imin;
    }
}

// ---- k_lossc: merge NP partials -> margin/ms/ls, then per-row loss ----
// one wave per row; lanes p=lane&31 each own one partial (duplicated halves)
__global__ __launch_bounds__(256) void k_lossc(
    const float* __restrict__ pmax, const float* __restrict__ pmin,
    const float* __restrict__ pZ, const int* __restrict__ pamax,
    const int* __restrict__ pamin, const float* __restrict__ w,
    float* __restrict__ vals) {
    const int wave = threadIdx.x >> 6;
    const int lane = threadIdx.x & 63;
    const int row = blockIdx.x * 4 + wave;
    const int p = lane & 31;
    const int o = p * CDIM + row;
    const float m0 = pmax[o];
    float v = m0; int a = pamax[o];
    float u = pmin[o]; int b = pamin[o];
#pragma unroll
    for (int msk = 1; msk < 32; msk <<= 1) {
        const float v2 = __shfl_xor(v, msk, 64);
        const int i2 = __shfl_xor(a, msk, 64);
        if (v2 > v || (v2 == v && i2 < a)) { v = v2; a = i2; }
        const float v3 = __shfl_xor(u, msk, 64);
        const int i3 = __shfl_xor(b, msk, 64);
        if (v3 < u || (v3 == u && i3 < b)) { u = v3; b = i3; }
    }
    float z = pZ[o] * __expf(m0 - v);
#pragma unroll
    for (int msk = 1; msk < 32; msk <<= 1) z += __shfl_xor(z, msk, 64);
    const float margin = (1.f - __expf(u - v)) / z;  // P[ms] - P[ls]
    const int jm = a, jl = b;

    const float4* wi = (const float4*)(w + (size_t)row * DDIM);
    const float4* wm = (const float4*)(w + (size_t)jm * DDIM);
    const float4* wl = (const float4*)(w + (size_t)jl * DDIM);
    float sm = 0.f, sl = 0.f;
#pragma unroll
    for (int h = 0; h < 2; ++h) {
        const int idx = h * 64 + lane;
        const float4 x = wi[idx];
        const float4 y = wm[idx];
        const float4 c = wl[idx];
        float d;
        d = x.x - y.x; sm = fmaf(d, d, sm);
        d = x.y - y.y; sm = fmaf(d, d, sm);
        d = x.z - y.z; sm = fmaf(d, d, sm);
        d = x.w - y.w; sm = fmaf(d, d, sm);
        d = x.x - c.x; sl = fmaf(d, d, sl);
        d = x.y - c.y; sl = fmaf(d, d, sl);
        d = x.z - c.z; sl = fmaf(d, d, sl);
        d = x.w - c.w; sl = fmaf(d, d, sl);
    }
#pragma unroll
    for (int msk = 1; msk < 64; msk <<= 1) {
        sm += __shfl_xor(sm, msk, 64);
        sl += __shfl_xor(sl, msk, 64);
    }
    if (lane == 0) {
        const float val = sqrtf(sm) - sqrtf(sl) + margin;
        vals[row] = val > 0.f ? val : 0.f;
    }
}

// ---- k_final: deterministic fixed-order mean (no atomics) ----
__global__ __launch_bounds__(256) void k_final(const float* __restrict__ vals,
                                               float* __restrict__ out) {
    __shared__ float red[256];
    float s = 0.f;
    for (int i = threadIdx.x; i < CDIM; i += 256) s += vals[i];
    red[threadIdx.x] = s;
    __syncthreads();
#pragma unroll
    for (int k = 128; k > 0; k >>= 1) {
        if (threadIdx.x < (unsigned)k) red[threadIdx.x] += red[threadIdx.x + k];
        __syncthreads();
    }
    if (threadIdx.x == 0) out[0] = red[0] * (1.0f / CDIM);
}

extern "C" void kernel_launch(void* const* d_in, const int* in_sizes, int n_in,
                              void* d_out, int out_size, void* d_ws, size_t ws_size,
                              hipStream_t stream) {
    const float* g = (const float*)d_in[0];  // gt_class_embeddings [8192,512]
    const float* w = (const float*)d_in[1];  // w [8192,512]
    float* out = (float*)d_out;

    // workspace layout (~21 MB)
    unsigned short* ghi = (unsigned short*)d_ws;
    unsigned short* glo = ghi + (size_t)CDIM * DDIM;
    float* p = (float*)(glo + (size_t)CDIM * DDIM);
    float* pmax = p;      p += NP * CDIM;
    float* pmin = p;      p += NP * CDIM;
    float* pZ = p;        p += NP * CDIM;
    int* pamax = (int*)p; p += NP * CDIM;
    int* pamin = (int*)p; p += NP * CDIM;
    float* vals = p;      p += CDIM;

    k_prep<<<CDIM / 4, 256, 0, stream>>>(g, ghi, glo);
    dim3 g2(CDIM / BM, CDIM / BN);
    k_simstats<<<g2, 256, 0, stream>>>(ghi, glo, pmax, pmin, pZ, pamax, pamin);
    k_lossc<<<CDIM / 4, 256, 0, stream>>>(pmax, pmin, pZ, pamax, pamin, w, vals);
    k_final<<<1, 256, 0, stream>>>(vals, out);
}